// Round 5
// baseline (240.670 us; speedup 1.0000x reference)
//
#include <hip/hip_runtime.h>

// CTC forward loss. T=1024, B=128, C=256, S=64, L=129.
// Producer/consumer block (2 waves per batch element):
//   wave 1 (producer): per time-step gathers lp[t][b][tgt_lane] and lp[t][b][0]
//     directly from global, computes exp() of both, stages {eml, ebl} float2
//     pairs into a 2-chunk LDS ring. All transcendentals + scattered reads
//     live on the producer's (idle) timeline.
//   wave 0 (consumer): alpha recurrence in SCALED LINEAR FP64:
//     p_s = exp(alpha_s) * 2^es   (es = wave-uniform int exponent)
//     lane i holds p[2i] ("pa"), p[2i+1] ("pb"); lane 63 also p[128] ("pc").
//     step: t = pa + pprev;  pa' = t*ebl;  pb' = (pb + (skip? t : pa))*eml;
//           pc' = (pc + pb)*ebl.   pprev = p[2i-1] via DPP wave_shr:1 (2x b32).
//   f64 range (2^±1022) >> the ~95-nat alpha spread across states that broke
//   fp32 accuracy (R4 absmax 1.5): rescale only every 32 steps, wave-uniform,
//   using an int-max DPP reduce over the doubles' hi words (positive IEEE
//   doubles order as ints). Rescale is exact power-of-2 => value-preserving.
//   act-freeze (t >= input_length) is wave-uniform -> scalar branch, no cndmask.

#define NEGV (-1e30f)
#define NEGH (-5e29f)

constexpr int T_  = 1024;
constexpr int C_  = 256;
constexpr int CH  = 64;        // rows per chunk
constexpr int NCH = T_ / CH;   // 16 chunks covering t = 1 .. 1024

__device__ __forceinline__ float lse2f(float x, float y) {
    float m = fmaxf(x, y);
    float s = __expf(x - m) + __expf(y - m);
    float r = m + __logf(s);
    return (m > NEGH) ? r : NEGV;
}

// double from lane i-1; lane 0 gets 0.0. Two b32 DPP wave_shr:1 (pure VALU).
__device__ __forceinline__ double dshr1(double x) {
    int lo = __double2loint(x), hi = __double2hiint(x);
    int plo = __builtin_amdgcn_update_dpp(0, lo, 0x138, 0xf, 0xf, false);
    int phi = __builtin_amdgcn_update_dpp(0, hi, 0x138, 0xf, 0xf, false);
    return __hiloint2double(phi, plo);
}

// one step of a DPP int-max reduction; old = x is identity under max
template <int CTRL>
__device__ __forceinline__ int dpp_imaxstep(int x) {
    int r = __builtin_amdgcn_update_dpp(x, x, CTRL, 0xf, 0xf, false);
    return max(x, r);
}

__global__ __launch_bounds__(128) void ctc_alpha_kernel(
    const float* __restrict__ lp,      // (T, B, C) log-probs
    const int* __restrict__ targets,   // (B*S,)
    const int* __restrict__ in_len,    // (B,)
    const int* __restrict__ tgt_len,   // (B,)
    float* __restrict__ partial,       // (B,) per-batch loss/tl
    int B, int S)
{
    __shared__ float2 stage[2][CH][64];   // 64 KiB emit-pair ring
    __shared__ float sh[132];

    const int b    = blockIdx.x;
    const int tid  = threadIdx.x;
    const int wave = tid >> 6;
    const int lane = tid & 63;
    const int BC   = B * C_;
    const float* rowb = lp + (size_t)b * C_;   // row at time t: rowb + t*BC

    int my_tgt = (lane < S) ? targets[b * S + lane] : 0;
    int prev_tgt = __shfl_up(my_tgt, 1);
    const bool skip = (lane > 0) && (my_tgt != prev_tgt) && (my_tgt != 0);
    const int ilen = in_len[b];

    // f64 linear-domain state: p = exp(alpha) * 2^es
    double pa = 0.0, pb = 0.0, pc = 0.0;
    int es = 0;
    if (wave == 0 && lane == 0) {
        pa = (double)__expf(rowb[0]);        // alpha0[0]
        pb = (double)__expf(rowb[my_tgt]);   // alpha0[1]
    }

    // producer prefill: chunk 0 = rows t = 1 .. CH
    if (wave == 1) {
#pragma unroll
        for (int r = 0; r < CH; ++r) {
            const size_t off = (size_t)(1 + r) * BC;
            float g  = rowb[off + my_tgt];
            float bl = rowb[off];
            stage[0][r][lane] = make_float2(__expf(g), __expf(bl));
        }
    }
    __syncthreads();   // chunk 0 staged

    for (int kc = 0; kc < NCH; ++kc) {
        if (wave == 1) {
            if (kc + 1 < NCH) {
                const int bufn = (kc + 1) & 1;
                const int t0 = 1 + (kc + 1) * CH;
#pragma unroll
                for (int r = 0; r < CH; ++r) {
                    int t = t0 + r;
                    t = (t > T_ - 1) ? (T_ - 1) : t;   // t=1024 unused; clamp
                    const size_t off = (size_t)t * BC;
                    float g  = rowb[off + my_tgt];
                    float bl = rowb[off];
                    stage[bufn][r][lane] = make_float2(__expf(g), __expf(bl));
                }
            }
        } else {
            const int buf = kc & 1;
            const int t0  = 1 + kc * CH;
#pragma unroll
            for (int r = 0; r < CH; ++r) {
                const int t = t0 + r;
                if (t < ilen) {                      // wave-uniform branch
                    float2 em = stage[buf][r][lane];
                    double eml = (double)em.x;
                    double ebl = (double)em.y;
                    double pprev = dshr1(pb);        // p[2i-1]
                    double ts = pa + pprev;
                    double nb = (pb + (skip ? ts : pa)) * eml;   // state 2i+1
                    double na = ts * ebl;                        // state 2i
                    double nc = (pc + pb) * ebl;                 // state 128
                    pa = na; pb = nb; pc = nc;
                    if ((r & 31) == 31) {
                        // wave-uniform power-of-2 rescale every 32 steps.
                        // positive doubles: hi-word int compare == f64 compare.
                        int h = max(max(__double2hiint(pa), __double2hiint(pb)),
                                    __double2hiint(pc));
                        h = dpp_imaxstep<0x111>(h);   // row_shr:1
                        h = dpp_imaxstep<0x112>(h);   // row_shr:2
                        h = dpp_imaxstep<0x114>(h);   // row_shr:4
                        h = dpp_imaxstep<0x118>(h);   // row_shr:8
                        h = dpp_imaxstep<0x142>(h);   // row_bcast:15
                        h = dpp_imaxstep<0x143>(h);   // row_bcast:31
                        int hm = __builtin_amdgcn_readlane(h, 63);
                        int e = ((hm >> 20) & 0x7ff) - 1023;
                        pa = ldexp(pa, -e);
                        pb = ldexp(pb, -e);
                        pc = ldexp(pc, -e);
                        es += e;
                    }
                }
            }
        }
        __syncthreads();   // chunk boundary: stage drained, buffers swap
    }

    // Epilogue: p (f64) + es -> log-domain float, lane 0 computes the loss
    if (wave == 0) {
        const double lses = (double)es * 0.6931471805599453;
        auto logp = [&](double p) -> float {
            if (p == 0.0) return NEGV;
            int hi = __double2hiint(p), lo = __double2loint(p);
            int E = ((hi >> 20) & 0x7ff) - 1023;
            int hin = (hi & (int)0x800FFFFF) | (1023 << 20);  // mantissa in [1,2)
            double m = __hiloint2double(hin, lo);
            return (float)(__logf((float)m) + ((double)E * 0.6931471805599453 + lses));
        };
        sh[2 * lane]     = logp(pa);
        sh[2 * lane + 1] = logp(pb);
        if (lane == 63) sh[128] = logp(pc);
    }
    __syncthreads();
    if (tid == 0) {
        int tl = tgt_len[b];
        int hi2 = 2 * tl;
        float ll = lse2f(sh[hi2], sh[hi2 - 1]);
        float loss = (ll > NEGH) ? -ll : 0.f;
        partial[b] = loss / (float)tl;
    }
}

__global__ __launch_bounds__(128) void ctc_reduce_kernel(
    const float* __restrict__ partial, float* __restrict__ out, int B)
{
    float v = 0.f;
    for (int j = threadIdx.x; j < B; j += 128) v += partial[j];
#pragma unroll
    for (int off = 32; off > 0; off >>= 1)
        v += __shfl_down(v, off);       // 64-lane wave reduce
    __shared__ float ws[2];
    if ((threadIdx.x & 63) == 0) ws[threadIdx.x >> 6] = v;
    __syncthreads();
    if (threadIdx.x == 0) out[0] = (ws[0] + ws[1]) / (float)B;
}

extern "C" void kernel_launch(void* const* d_in, const int* in_sizes, int n_in,
                              void* d_out, int out_size, void* d_ws, size_t ws_size,
                              hipStream_t stream)
{
    const float* lp      = (const float*)d_in[0];  // (T,B,C) float32
    const int*   targets = (const int*)d_in[1];    // (B*S,)  int32
    const int*   il      = (const int*)d_in[2];    // (B,)
    const int*   tl      = (const int*)d_in[3];    // (B,)
    const int B = in_sizes[2];
    const int S = in_sizes[1] / B;

    float* partial = (float*)d_ws;     // B floats of scratch

    ctc_alpha_kernel<<<B, 128, 0, stream>>>(lp, targets, il, tl, partial, B, S);
    ctc_reduce_kernel<<<1, 128, 0, stream>>>(partial, (float*)d_out, B);
}

// Round 6
// 238.992 us; speedup vs baseline: 1.0070x; 1.0070x over previous
//
#include <hip/hip_runtime.h>

// CTC forward loss. T=1024, B=128, C=256, S=64, L=129.
// Producer/consumer block (2 waves per batch element):
//   wave 1 (producer): per time-step gathers lp[t][b][tgt_lane] and lp[t][b][0]
//     directly from global, computes exp() of both, stages {eml, ebl} float2
//     pairs into a 2-chunk LDS ring. All transcendentals + scattered reads
//     live on the producer's (idle) timeline.
//   wave 0 (consumer): alpha recurrence in SCALED LINEAR FP64:
//     p_s = exp(alpha_s) * 2^es   (es = wave-uniform int exponent)
//     lane i holds p[2i] ("pa"), p[2i+1] ("pb"); lane 63 also p[128] ("pc").
//     step: ts = pa + pprev;  pa' = ts*ebl;  pb' = (pb + (skip? ts : pa))*eml;
//           pc' = (pc + pb)*ebl.   pprev = p[2i-1] via DPP wave_shr:1 (2x b32).
//   R5->R6: consumer reads its emit pairs in BATCHES OF 8 ds_read_b64 before
//   computing 8 steps — 8 loads pipelined in-order hides the ~120-cycle LDS
//   latency that was serialized per-step in R5 (232 cyc/step observed).
//   f64 range (2^±1022) swallows the ~95-nat cross-state alpha spread that
//   broke fp32 (R4 absmax 1.5): rescale every 32 steps, wave-uniform, via an
//   int-max DPP reduce over the doubles' hi words (positive IEEE doubles
//   order as ints). Power-of-2 rescale is exact => value-preserving.

#define NEGV (-1e30f)
#define NEGH (-5e29f)

constexpr int T_  = 1024;
constexpr int C_  = 256;
constexpr int CH  = 64;        // rows per chunk
constexpr int NCH = T_ / CH;   // 16 chunks covering t = 1 .. 1024
constexpr int BA  = 8;         // consumer load batch (ds_reads in flight)

__device__ __forceinline__ float lse2f(float x, float y) {
    float m = fmaxf(x, y);
    float s = __expf(x - m) + __expf(y - m);
    float r = m + __logf(s);
    return (m > NEGH) ? r : NEGV;
}

// double from lane i-1; lane 0 gets 0.0. Two b32 DPP wave_shr:1 (pure VALU).
__device__ __forceinline__ double dshr1(double x) {
    int lo = __double2loint(x), hi = __double2hiint(x);
    int plo = __builtin_amdgcn_update_dpp(0, lo, 0x138, 0xf, 0xf, false);
    int phi = __builtin_amdgcn_update_dpp(0, hi, 0x138, 0xf, 0xf, false);
    return __hiloint2double(phi, plo);
}

// one step of a DPP int-max reduction; old = x is identity under max
template <int CTRL>
__device__ __forceinline__ int dpp_imaxstep(int x) {
    int r = __builtin_amdgcn_update_dpp(x, x, CTRL, 0xf, 0xf, false);
    return max(x, r);
}

__global__ __launch_bounds__(128) void ctc_alpha_kernel(
    const float* __restrict__ lp,      // (T, B, C) log-probs
    const int* __restrict__ targets,   // (B*S,)
    const int* __restrict__ in_len,    // (B,)
    const int* __restrict__ tgt_len,   // (B,)
    float* __restrict__ partial,       // (B,) per-batch loss/tl
    int B, int S)
{
    __shared__ float2 stage[2][CH][64];   // 64 KiB emit-pair ring
    __shared__ float sh[132];

    const int b    = blockIdx.x;
    const int tid  = threadIdx.x;
    const int wave = tid >> 6;
    const int lane = tid & 63;
    const int BC   = B * C_;
    const float* rowb = lp + (size_t)b * C_;   // row at time t: rowb + t*BC

    int my_tgt = (lane < S) ? targets[b * S + lane] : 0;
    int prev_tgt = __shfl_up(my_tgt, 1);
    const bool skip = (lane > 0) && (my_tgt != prev_tgt) && (my_tgt != 0);
    const int ilen = in_len[b];

    // f64 linear-domain state: p = exp(alpha) * 2^es
    double pa = 0.0, pb = 0.0, pc = 0.0;
    int es = 0;
    if (wave == 0 && lane == 0) {
        pa = (double)__expf(rowb[0]);        // alpha0[0]
        pb = (double)__expf(rowb[my_tgt]);   // alpha0[1]
    }

    // producer prefill: chunk 0 = rows t = 1 .. CH
    if (wave == 1) {
#pragma unroll
        for (int r = 0; r < CH; ++r) {
            const size_t off = (size_t)(1 + r) * BC;
            float g  = rowb[off + my_tgt];
            float bl = rowb[off];
            stage[0][r][lane] = make_float2(__expf(g), __expf(bl));
        }
    }
    __syncthreads();   // chunk 0 staged

    for (int kc = 0; kc < NCH; ++kc) {
        if (wave == 1) {
            if (kc + 1 < NCH) {
                const int bufn = (kc + 1) & 1;
                const int t0 = 1 + (kc + 1) * CH;
#pragma unroll
                for (int r = 0; r < CH; ++r) {
                    int t = t0 + r;
                    t = (t > T_ - 1) ? (T_ - 1) : t;   // t=1024 unused; clamp
                    const size_t off = (size_t)t * BC;
                    float g  = rowb[off + my_tgt];
                    float bl = rowb[off];
                    stage[bufn][r][lane] = make_float2(__expf(g), __expf(bl));
                }
            }
        } else {
            const int buf = kc & 1;
            const int t0  = 1 + kc * CH;
#pragma unroll
            for (int r8 = 0; r8 < CH; r8 += BA) {
                // issue BA ds_read_b64 back-to-back: in-order return means
                // only the first use pays the LDS latency.
                float2 em[BA];
#pragma unroll
                for (int j = 0; j < BA; ++j)
                    em[j] = stage[buf][r8 + j][lane];
#pragma unroll
                for (int j = 0; j < BA; ++j) {
                    const int r = r8 + j;
                    const int t = t0 + r;
                    if (t < ilen) {                  // wave-uniform branch
                        double eml = (double)em[j].x;
                        double ebl = (double)em[j].y;
                        double pprev = dshr1(pb);    // p[2i-1]
                        double ts = pa + pprev;
                        double nb = (pb + (skip ? ts : pa)) * eml;  // 2i+1
                        double na = ts * ebl;                       // 2i
                        double nc = (pc + pb) * ebl;                // 128
                        pa = na; pb = nb; pc = nc;
                        if ((r & 31) == 31) {
                            // wave-uniform power-of-2 rescale every 32 steps.
                            int h = max(max(__double2hiint(pa), __double2hiint(pb)),
                                        __double2hiint(pc));
                            h = dpp_imaxstep<0x111>(h);   // row_shr:1
                            h = dpp_imaxstep<0x112>(h);   // row_shr:2
                            h = dpp_imaxstep<0x114>(h);   // row_shr:4
                            h = dpp_imaxstep<0x118>(h);   // row_shr:8
                            h = dpp_imaxstep<0x142>(h);   // row_bcast:15
                            h = dpp_imaxstep<0x143>(h);   // row_bcast:31
                            int hm = __builtin_amdgcn_readlane(h, 63);
                            int e = ((hm >> 20) & 0x7ff) - 1023;
                            pa = ldexp(pa, -e);
                            pb = ldexp(pb, -e);
                            pc = ldexp(pc, -e);
                            es += e;
                        }
                    }
                }
            }
        }
        __syncthreads();   // chunk boundary: stage drained, buffers swap
    }

    // Epilogue: p (f64) + es -> log-domain float, lane 0 computes the loss
    if (wave == 0) {
        const double lses = (double)es * 0.6931471805599453;
        auto logp = [&](double p) -> float {
            if (p == 0.0) return NEGV;
            int hi = __double2hiint(p), lo = __double2loint(p);
            int E = ((hi >> 20) & 0x7ff) - 1023;
            int hin = (hi & (int)0x800FFFFF) | (1023 << 20);  // mantissa in [1,2)
            double m = __hiloint2double(hin, lo);
            return (float)(__logf((float)m) + ((double)E * 0.6931471805599453 + lses));
        };
        sh[2 * lane]     = logp(pa);
        sh[2 * lane + 1] = logp(pb);
        if (lane == 63) sh[128] = logp(pc);
    }
    __syncthreads();
    if (tid == 0) {
        int tl = tgt_len[b];
        int hi2 = 2 * tl;
        float ll = lse2f(sh[hi2], sh[hi2 - 1]);
        float loss = (ll > NEGH) ? -ll : 0.f;
        partial[b] = loss / (float)tl;
    }
}

__global__ __launch_bounds__(128) void ctc_reduce_kernel(
    const float* __restrict__ partial, float* __restrict__ out, int B)
{
    float v = 0.f;
    for (int j = threadIdx.x; j < B; j += 128) v += partial[j];
#pragma unroll
    for (int off = 32; off > 0; off >>= 1)
        v += __shfl_down(v, off);       // 64-lane wave reduce
    __shared__ float ws[2];
    if ((threadIdx.x & 63) == 0) ws[threadIdx.x >> 6] = v;
    __syncthreads();
    if (threadIdx.x == 0) out[0] = (ws[0] + ws[1]) / (float)B;
}

extern "C" void kernel_launch(void* const* d_in, const int* in_sizes, int n_in,
                              void* d_out, int out_size, void* d_ws, size_t ws_size,
                              hipStream_t stream)
{
    const float* lp      = (const float*)d_in[0];  // (T,B,C) float32
    const int*   targets = (const int*)d_in[1];    // (B*S,)  int32
    const int*   il      = (const int*)d_in[2];    // (B,)
    const int*   tl      = (const int*)d_in[3];    // (B,)
    const int B = in_sizes[2];
    const int S = in_sizes[1] / B;

    float* partial = (float*)d_ws;     // B floats of scratch

    ctc_alpha_kernel<<<B, 128, 0, stream>>>(lp, targets, il, tl, partial, B, S);
    ctc_reduce_kernel<<<1, 128, 0, stream>>>(partial, (float*)d_out, B);
}

// Round 7
// 201.008 us; speedup vs baseline: 1.1973x; 1.1890x over previous
//
#include <hip/hip_runtime.h>

// CTC forward loss. T=1024, B=128, C=256, S=64, L=129.
// 3 waves per block (one block per batch element):
//   waves 1-2 (producers): gather lp[t][b][tgt_lane] + lp[t][b][0] from
//     global, exp() both, stage {eml, ebl} float2 into a 2-chunk LDS ring.
//     32 rows per producer wave per chunk -> fill time ~1/2 of consumer time.
//   wave 0 (consumer): alpha recurrence in SCALED LINEAR FP64:
//     p_s = exp(alpha_s) * 2^es (es = wave-uniform int exponent).
//     lane i holds p[2i] ("pa"), p[2i+1] ("pb"); lane 63 also p[128] ("pc").
//     LDS reads are software-pipelined with NAMED rotating float2 registers
//     (distance 4) — R6 showed an indexed local array is not promoted
//     (scratch round-trips, 99->120us); R5 showed loads behind per-step
//     branches serialize ~120cyc LDS latency per step. Loads here are
//     unconditional and ahead of use; act-masking is a wave-uniform branch
//     inside the step only (taken apart only in the boundary chunk).
//   Rescale every 32 steps: int-max DPP over f64 hi-words (positive doubles
//   order as ints), readlane, exact power-of-2 ldexp => value-preserving.

#define NEGV (-1e30f)
#define NEGH (-5e29f)

constexpr int T_  = 1024;
constexpr int C_  = 256;
constexpr int CH  = 64;        // rows per chunk
constexpr int NCH = T_ / CH;   // 16 chunks covering t = 1 .. 1024
constexpr int PD  = 4;         // consumer prefetch distance (named regs)

__device__ __forceinline__ float lse2f(float x, float y) {
    float m = fmaxf(x, y);
    float s = __expf(x - m) + __expf(y - m);
    float r = m + __logf(s);
    return (m > NEGH) ? r : NEGV;
}

// double from lane i-1; lane 0 gets 0.0. Two b32 DPP wave_shr:1 (pure VALU).
__device__ __forceinline__ double dshr1(double x) {
    int lo = __double2loint(x), hi = __double2hiint(x);
    int plo = __builtin_amdgcn_update_dpp(0, lo, 0x138, 0xf, 0xf, false);
    int phi = __builtin_amdgcn_update_dpp(0, hi, 0x138, 0xf, 0xf, false);
    return __hiloint2double(phi, plo);
}

// one step of a DPP int-max reduction; old = x is identity under max
template <int CTRL>
__device__ __forceinline__ int dpp_imaxstep(int x) {
    int r = __builtin_amdgcn_update_dpp(x, x, CTRL, 0xf, 0xf, false);
    return max(x, r);
}

__global__ __launch_bounds__(192) void ctc_alpha_kernel(
    const float* __restrict__ lp,      // (T, B, C) log-probs
    const int* __restrict__ targets,   // (B*S,)
    const int* __restrict__ in_len,    // (B,)
    const int* __restrict__ tgt_len,   // (B,)
    float* __restrict__ partial,       // (B,) per-batch loss/tl
    int B, int S)
{
    __shared__ float2 stage[2][CH][64];   // 64 KiB emit-pair ring
    __shared__ float sh[132];

    const int b    = blockIdx.x;
    const int tid  = threadIdx.x;
    const int wave = tid >> 6;
    const int lane = tid & 63;
    const int BC   = B * C_;
    const float* rowb = lp + (size_t)b * C_;   // row at time t: rowb + t*BC

    int my_tgt = (lane < S) ? targets[b * S + lane] : 0;
    int prev_tgt = __shfl_up(my_tgt, 1);
    const bool skip = (lane > 0) && (my_tgt != prev_tgt) && (my_tgt != 0);
    const double skipd = skip ? 1.0 : 0.0;
    const int ilen = in_len[b];

    // f64 linear-domain state: p = exp(alpha) * 2^es
    double pa = 0.0, pb = 0.0, pc = 0.0;
    int es = 0;
    if (wave == 0 && lane == 0) {
        pa = (double)__expf(rowb[0]);        // alpha0[0]
        pb = (double)__expf(rowb[my_tgt]);   // alpha0[1]
    }

    // producers prefill chunk 0 (rows t = 1 .. CH), 32 rows per wave
    if (wave >= 1) {
        const int r0 = (wave - 1) * (CH / 2);
#pragma unroll
        for (int r = 0; r < CH / 2; ++r) {
            int t = 1 + r0 + r;
            const size_t off = (size_t)t * BC;
            float g  = rowb[off + my_tgt];
            float bl = rowb[off];
            stage[0][r0 + r][lane] = make_float2(__expf(g), __expf(bl));
        }
    }
    __syncthreads();   // chunk 0 staged

    for (int kc = 0; kc < NCH; ++kc) {
        if (wave >= 1) {
            if (kc + 1 < NCH) {
                const int bufn = (kc + 1) & 1;
                const int r0 = (wave - 1) * (CH / 2);
                const int t0 = 1 + (kc + 1) * CH + r0;
#pragma unroll
                for (int r = 0; r < CH / 2; ++r) {
                    int t = t0 + r;
                    t = (t > T_ - 1) ? (T_ - 1) : t;   // t=1024 unused; clamp
                    const size_t off = (size_t)t * BC;
                    float g  = rowb[off + my_tgt];
                    float bl = rowb[off];
                    stage[bufn][r0 + r][lane] = make_float2(__expf(g), __expf(bl));
                }
            }
        } else {
            const int t0 = 1 + kc * CH;
            if (t0 < ilen) {
                const float2* sb = &stage[kc & 1][0][lane];  // row stride 64
                // named rotating prefetch registers, distance PD=4
                float2 f0 = sb[0 * 64];
                float2 f1 = sb[1 * 64];
                float2 f2 = sb[2 * 64];
                float2 f3 = sb[3 * 64];
#pragma unroll
                for (int r = 0; r < CH; ++r) {
                    float2 cur = f0;
                    f0 = f1; f1 = f2; f2 = f3;
                    if (r + PD < CH) f3 = sb[(r + PD) * 64];
                    if (t0 + r < ilen) {             // wave-uniform branch
                        double eml = (double)cur.x;
                        double ebl = (double)cur.y;
                        double pprev = dshr1(pb);    // p[2i-1]
                        double u  = fma(skipd, pprev, pa);   // pa + skip*pprev
                        double nb = (pb + u) * eml;          // state 2i+1
                        double na = (pa + pprev) * ebl;      // state 2i
                        double nc = (pc + pb) * ebl;         // state 128
                        pa = na; pb = nb; pc = nc;
                        if ((r & 31) == 31) {
                            // wave-uniform power-of-2 rescale every 32 steps
                            int h = max(max(__double2hiint(pa), __double2hiint(pb)),
                                        __double2hiint(pc));
                            h = dpp_imaxstep<0x111>(h);   // row_shr:1
                            h = dpp_imaxstep<0x112>(h);   // row_shr:2
                            h = dpp_imaxstep<0x114>(h);   // row_shr:4
                            h = dpp_imaxstep<0x118>(h);   // row_shr:8
                            h = dpp_imaxstep<0x142>(h);   // row_bcast:15
                            h = dpp_imaxstep<0x143>(h);   // row_bcast:31
                            int hm = __builtin_amdgcn_readlane(h, 63);
                            int e = ((hm >> 20) & 0x7ff) - 1023;
                            pa = ldexp(pa, -e);
                            pb = ldexp(pb, -e);
                            pc = ldexp(pc, -e);
                            es += e;
                        }
                    }
                }
            }
        }
        __syncthreads();   // chunk boundary: stage drained, buffers swap
    }

    // Epilogue: p (f64) + es -> log-domain float, lane 0 computes the loss
    if (wave == 0) {
        const double lses = (double)es * 0.6931471805599453;
        auto logp = [&](double p) -> float {
            if (p == 0.0) return NEGV;
            int hi = __double2hiint(p), lo = __double2loint(p);
            int E = ((hi >> 20) & 0x7ff) - 1023;
            int hin = (hi & (int)0x800FFFFF) | (1023 << 20);  // mantissa in [1,2)
            double m = __hiloint2double(hin, lo);
            return (float)(__logf((float)m) + ((double)E * 0.6931471805599453 + lses));
        };
        sh[2 * lane]     = logp(pa);
        sh[2 * lane + 1] = logp(pb);
        if (lane == 63) sh[128] = logp(pc);
    }
    __syncthreads();
    if (tid == 0) {
        int tl = tgt_len[b];
        int hi2 = 2 * tl;
        float ll = lse2f(sh[hi2], sh[hi2 - 1]);
        float loss = (ll > NEGH) ? -ll : 0.f;
        partial[b] = loss / (float)tl;
    }
}

__global__ __launch_bounds__(128) void ctc_reduce_kernel(
    const float* __restrict__ partial, float* __restrict__ out, int B)
{
    float v = 0.f;
    for (int j = threadIdx.x; j < B; j += 128) v += partial[j];
#pragma unroll
    for (int off = 32; off > 0; off >>= 1)
        v += __shfl_down(v, off);       // 64-lane wave reduce
    __shared__ float ws[2];
    if ((threadIdx.x & 63) == 0) ws[threadIdx.x >> 6] = v;
    __syncthreads();
    if (threadIdx.x == 0) out[0] = (ws[0] + ws[1]) / (float)B;
}

extern "C" void kernel_launch(void* const* d_in, const int* in_sizes, int n_in,
                              void* d_out, int out_size, void* d_ws, size_t ws_size,
                              hipStream_t stream)
{
    const float* lp      = (const float*)d_in[0];  // (T,B,C) float32
    const int*   targets = (const int*)d_in[1];    // (B*S,)  int32
    const int*   il      = (const int*)d_in[2];    // (B,)
    const int*   tl      = (const int*)d_in[3];    // (B,)
    const int B = in_sizes[2];
    const int S = in_sizes[1] / B;

    float* partial = (float*)d_ws;     // B floats of scratch

    ctc_alpha_kernel<<<B, 192, 0, stream>>>(lp, targets, il, tl, partial, B, S);
    ctc_reduce_kernel<<<1, 128, 0, stream>>>(partial, (float*)d_out, B);
}

// Round 8
// 197.618 us; speedup vs baseline: 1.2179x; 1.0172x over previous
//
#include <hip/hip_runtime.h>

// CTC forward loss. T=1024, B=128, C=256, S=64, L=129.
// 3 waves per block (one block per batch element):
//   waves 1-2 (producers): gather lp[t][b][tgt_lane] + lp[t][b][0], exp()
//     both, stage {eml, ebl} float2 into a 2-chunk LDS ring. R8: producer is
//     software-pipelined with NAMED register sets (8 rows = 16 floats per
//     set, two sets ping-ponged) so ~32 global loads stay in flight; R7's
//     producer serialized load->exp per row (~300 cyc x 32 rows/chunk) and
//     was the real barrier-side stall (R6->R7 producer split bought exactly
//     the predicted halving).
//   wave 0 (consumer): alpha recurrence in SCALED LINEAR FP64:
//     p_s = exp(alpha_s) * 2^es (es = wave-uniform int exponent).
//     lane i holds p[2i] ("pa"), p[2i+1] ("pb"); lane 63 also p[128] ("pc").
//     ds_reads pipelined with named rotating float2 regs (distance 4).
//     Fast path (chunk fully < ilen): NO per-step branch. Masked path only
//     for the boundary chunk.
//   Rescale every 32 steps: int-max DPP over f64 hi-words (positive doubles
//   order as ints), readlane, exact power-of-2 ldexp => value-preserving.

#define NEGV (-1e30f)
#define NEGH (-5e29f)

constexpr int T_  = 1024;
constexpr int C_  = 256;
constexpr int CH  = 64;        // rows per chunk
constexpr int NCH = T_ / CH;   // 16 chunks covering t = 1 .. 1024

__device__ __forceinline__ float lse2f(float x, float y) {
    float m = fmaxf(x, y);
    float s = __expf(x - m) + __expf(y - m);
    float r = m + __logf(s);
    return (m > NEGH) ? r : NEGV;
}

// double from lane i-1; lane 0 gets 0.0. Two b32 DPP wave_shr:1 (pure VALU).
__device__ __forceinline__ double dshr1(double x) {
    int lo = __double2loint(x), hi = __double2hiint(x);
    int plo = __builtin_amdgcn_update_dpp(0, lo, 0x138, 0xf, 0xf, false);
    int phi = __builtin_amdgcn_update_dpp(0, hi, 0x138, 0xf, 0xf, false);
    return __hiloint2double(phi, plo);
}

// one step of a DPP int-max reduction; old = x is identity under max
template <int CTRL>
__device__ __forceinline__ int dpp_imaxstep(int x) {
    int r = __builtin_amdgcn_update_dpp(x, x, CTRL, 0xf, 0xf, false);
    return max(x, r);
}

// ---- producer register-set macros (named regs; R6: arrays are NOT promoted)
#define PDECL(S) float S##g0,S##g1,S##g2,S##g3,S##g4,S##g5,S##g6,S##g7, \
                       S##l0,S##l1,S##l2,S##l3,S##l4,S##l5,S##l6,S##l7
#define PLOAD1(S,J,TB) { int t_ = (TB) + J; t_ = t_ > 1023 ? 1023 : t_;      \
    const float* rp_ = rowb + (size_t)t_ * BC;                               \
    S##g##J = rp_[my_tgt]; S##l##J = rp_[0]; }
#define PLOAD(S,TB) PLOAD1(S,0,TB) PLOAD1(S,1,TB) PLOAD1(S,2,TB)             \
                    PLOAD1(S,3,TB) PLOAD1(S,4,TB) PLOAD1(S,5,TB)             \
                    PLOAD1(S,6,TB) PLOAD1(S,7,TB)
#define PSTORE1(S,J,RB,BUFP) BUFP[((RB) + J) * 64 + lane] =                  \
    make_float2(__expf(S##g##J), __expf(S##l##J));
#define PSTORE(S,RB,BUFP) PSTORE1(S,0,RB,BUFP) PSTORE1(S,1,RB,BUFP)          \
                          PSTORE1(S,2,RB,BUFP) PSTORE1(S,3,RB,BUFP)          \
                          PSTORE1(S,4,RB,BUFP) PSTORE1(S,5,RB,BUFP)          \
                          PSTORE1(S,6,RB,BUFP) PSTORE1(S,7,RB,BUFP)
// 32 rows, 8-row groups, two sets ping-ponged: loads of group k+1 are issued
// before the exp/write of group k -> ~32 loads in flight.
#define PRODUCE32(TSTART,RBASE,BUFP) {                                       \
    PDECL(A); PDECL(Bx);                                                     \
    PLOAD(A,  (TSTART));                                                     \
    PLOAD(Bx, (TSTART) + 8);                                                 \
    PSTORE(A,  (RBASE), BUFP);                                               \
    PLOAD(A,  (TSTART) + 16);                                                \
    PSTORE(Bx, (RBASE) + 8, BUFP);                                           \
    PLOAD(Bx, (TSTART) + 24);                                                \
    PSTORE(A,  (RBASE) + 16, BUFP);                                          \
    PSTORE(Bx, (RBASE) + 24, BUFP); }

__global__ __launch_bounds__(192) void ctc_alpha_kernel(
    const float* __restrict__ lp,      // (T, B, C) log-probs
    const int* __restrict__ targets,   // (B*S,)
    const int* __restrict__ in_len,    // (B,)
    const int* __restrict__ tgt_len,   // (B,)
    float* __restrict__ partial,       // (B,) per-batch loss/tl
    int B, int S)
{
    __shared__ float2 stage[2][CH * 64];   // 64 KiB emit-pair ring
    __shared__ float sh[132];

    const int b    = blockIdx.x;
    const int tid  = threadIdx.x;
    const int wave = tid >> 6;
    const int lane = tid & 63;
    const int BC   = B * C_;
    const float* rowb = lp + (size_t)b * C_;   // row at time t: rowb + t*BC

    int my_tgt = (lane < S) ? targets[b * S + lane] : 0;
    int prev_tgt = __shfl_up(my_tgt, 1);
    const bool skip = (lane > 0) && (my_tgt != prev_tgt) && (my_tgt != 0);
    const double skipd = skip ? 1.0 : 0.0;
    const int ilen = in_len[b];

    // f64 linear-domain state: p = exp(alpha) * 2^es
    double pa = 0.0, pb = 0.0, pc = 0.0;
    int es = 0;
    if (wave == 0 && lane == 0) {
        pa = (double)__expf(rowb[0]);        // alpha0[0]
        pb = (double)__expf(rowb[my_tgt]);   // alpha0[1]
    }

    // producers prefill chunk 0 (rows t = 1 .. CH), 32 rows per wave
    if (wave >= 1) {
        const int r0 = (wave - 1) * 32;
        float2* bp = &stage[0][0];
        PRODUCE32(1 + r0, r0, bp);
    }
    __syncthreads();   // chunk 0 staged

#define STEP(cur) {                                                          \
        double eml = (double)(cur).x;                                        \
        double ebl = (double)(cur).y;                                        \
        double pprev = dshr1(pb);            /* p[2i-1] */                   \
        double u  = fma(skipd, pprev, pa);   /* pa + skip*pprev */           \
        double nb = (pb + u) * eml;          /* state 2i+1 */                \
        double na = (pa + pprev) * ebl;      /* state 2i   */                \
        double nc = (pc + pb) * ebl;         /* state 128  */                \
        pa = na; pb = nb; pc = nc; }

#define RESCALE() {                                                          \
        int h = max(max(__double2hiint(pa), __double2hiint(pb)),             \
                    __double2hiint(pc));                                     \
        h = dpp_imaxstep<0x111>(h);   /* row_shr:1   */                      \
        h = dpp_imaxstep<0x112>(h);   /* row_shr:2   */                      \
        h = dpp_imaxstep<0x114>(h);   /* row_shr:4   */                      \
        h = dpp_imaxstep<0x118>(h);   /* row_shr:8   */                      \
        h = dpp_imaxstep<0x142>(h);   /* row_bcast:15*/                      \
        h = dpp_imaxstep<0x143>(h);   /* row_bcast:31*/                      \
        int hm = __builtin_amdgcn_readlane(h, 63);                           \
        int e = ((hm >> 20) & 0x7ff) - 1023;                                 \
        pa = ldexp(pa, -e); pb = ldexp(pb, -e); pc = ldexp(pc, -e);          \
        es += e; }

    for (int kc = 0; kc < NCH; ++kc) {
        if (wave >= 1) {
            if (kc + 1 < NCH) {
                const int r0 = (wave - 1) * 32;
                const int t0 = 1 + (kc + 1) * CH + r0;
                float2* bp = &stage[(kc + 1) & 1][0];
                PRODUCE32(t0, r0, bp);
            }
        } else {
            const int t0 = 1 + kc * CH;
            const float2* sb = &stage[kc & 1][lane];   // row stride 64
            if (t0 + CH <= ilen) {
                // fast path: every step active -> no per-step branch
                float2 f0 = sb[0 * 64];
                float2 f1 = sb[1 * 64];
                float2 f2 = sb[2 * 64];
                float2 f3 = sb[3 * 64];
#pragma unroll
                for (int r = 0; r < CH; ++r) {
                    float2 cur = f0;
                    f0 = f1; f1 = f2; f2 = f3;
                    if (r + 4 < CH) f3 = sb[(r + 4) * 64];
                    STEP(cur);
                    if ((r & 31) == 31) RESCALE();
                }
            } else if (t0 < ilen) {
                // boundary chunk: wave-uniform per-step mask
                float2 f0 = sb[0 * 64];
                float2 f1 = sb[1 * 64];
                float2 f2 = sb[2 * 64];
                float2 f3 = sb[3 * 64];
#pragma unroll
                for (int r = 0; r < CH; ++r) {
                    float2 cur = f0;
                    f0 = f1; f1 = f2; f2 = f3;
                    if (r + 4 < CH) f3 = sb[(r + 4) * 64];
                    if (t0 + r < ilen) {
                        STEP(cur);
                        if ((r & 31) == 31) RESCALE();
                    }
                }
            }
        }
        __syncthreads();   // chunk boundary: stage drained, buffers swap
    }

    // Epilogue: p (f64) + es -> log-domain float, lane 0 computes the loss
    if (wave == 0) {
        const double lses = (double)es * 0.6931471805599453;
        auto logp = [&](double p) -> float {
            if (p == 0.0) return NEGV;
            int hi = __double2hiint(p), lo = __double2loint(p);
            int E = ((hi >> 20) & 0x7ff) - 1023;
            int hin = (hi & (int)0x800FFFFF) | (1023 << 20);  // mantissa in [1,2)
            double m = __hiloint2double(hin, lo);
            return (float)(__logf((float)m) + ((double)E * 0.6931471805599453 + lses));
        };
        sh[2 * lane]     = logp(pa);
        sh[2 * lane + 1] = logp(pb);
        if (lane == 63) sh[128] = logp(pc);
    }
    __syncthreads();
    if (tid == 0) {
        int tl = tgt_len[b];
        int hi2 = 2 * tl;
        float ll = lse2f(sh[hi2], sh[hi2 - 1]);
        float loss = (ll > NEGH) ? -ll : 0.f;
        partial[b] = loss / (float)tl;
    }
}

__global__ __launch_bounds__(128) void ctc_reduce_kernel(
    const float* __restrict__ partial, float* __restrict__ out, int B)
{
    float v = 0.f;
    for (int j = threadIdx.x; j < B; j += 128) v += partial[j];
#pragma unroll
    for (int off = 32; off > 0; off >>= 1)
        v += __shfl_down(v, off);       // 64-lane wave reduce
    __shared__ float ws[2];
    if ((threadIdx.x & 63) == 0) ws[threadIdx.x >> 6] = v;
    __syncthreads();
    if (threadIdx.x == 0) out[0] = (ws[0] + ws[1]) / (float)B;
}

extern "C" void kernel_launch(void* const* d_in, const int* in_sizes, int n_in,
                              void* d_out, int out_size, void* d_ws, size_t ws_size,
                              hipStream_t stream)
{
    const float* lp      = (const float*)d_in[0];  // (T,B,C) float32
    const int*   targets = (const int*)d_in[1];    // (B*S,)  int32
    const int*   il      = (const int*)d_in[2];    // (B,)
    const int*   tl      = (const int*)d_in[3];    // (B,)
    const int B = in_sizes[2];
    const int S = in_sizes[1] / B;

    float* partial = (float*)d_ws;     // B floats of scratch

    ctc_alpha_kernel<<<B, 192, 0, stream>>>(lp, targets, il, tl, partial, B, S);
    ctc_reduce_kernel<<<1, 128, 0, stream>>>(partial, (float*)d_out, B);
}